// Round 4
// baseline (1699.772 us; speedup 1.0000x reference)
//
#include <hip/hip_runtime.h>
#include <hip/hip_bf16.h>

#define NN 50000
#define NE 800000
#define EMB 64
#define NH 8
#define HD 8
#define MAXD 100
#define SCALE 0.35355339059327373f

// ws layout (floats):
//   accum [NN*EMB] | denom [NN*NH] | q [NN*EMB] | k [NN*EMB] | v [NN*EMB] | flags[16]
// flags: f0=qkv ran, f1=edge ran, f3=out-of-range row/col count,
//        f5=x-looks-fp32 count (of 1024), f6=ei-looks-int64 count (of 1024)

// ---- diagnostic: fill d_out with a constant (env-check sentinels)
__global__ __launch_bounds__(256) void fill_kernel(float* __restrict__ out, long n, float val) {
    long i = (long)blockIdx.x * 256 + threadIdx.x;
    if (i < n) out[i] = val;
}

// ---- zero accum + denom
__global__ __launch_bounds__(256) void init_kernel(float* __restrict__ p, long n) {
    long i = (long)blockIdx.x * 256 + threadIdx.x;
    if (i < n) p[i] = 0.0f;
}

// ---- dtype sniffer: 1 block. Zeroes flags, tests x-as-fp32 and ei-as-int64.
__global__ __launch_bounds__(256) void sniff_kernel(const unsigned* __restrict__ xu,
                                                    const int* __restrict__ ei,
                                                    float* __restrict__ flags) {
    int t = threadIdx.x;
    if (t < 16) flags[t] = 0.0f;
    __syncthreads();
    int c_f32 = 0, c_i64 = 0;
    for (int i = t; i < 1024; i += 256) {
        union { unsigned u; float f; } w; w.u = xu[i];
        float av = fabsf(w.f);
        if (av >= 1e-3f && av <= 100.0f) c_f32++;   // N(0,1) fp32 lands here ~99.9%
        if (ei[2 * i + 1] == 0) c_i64++;            // int64<2^31 -> odd dwords all 0
    }
    atomicAdd(&flags[5], (float)c_f32);
    atomicAdd(&flags[6], (float)c_i64);
}

// ---- QKV: per-node y = x @ W + b; 4 nodes per 256-thread block
__global__ __launch_bounds__(256) void qkv_kernel(
    const float* __restrict__ x,
    const float* __restrict__ Wq, const float* __restrict__ bq,
    const float* __restrict__ Wk, const float* __restrict__ bk,
    const float* __restrict__ Wv, const float* __restrict__ bv,
    float* __restrict__ q, float* __restrict__ k, float* __restrict__ v,
    float* __restrict__ flags)
{
    if (blockIdx.x == 0 && threadIdx.x == 0) flags[0] = 1.0f;
    __shared__ float xs[4 * EMB];
    int t = threadIdx.x;
    long base = (long)blockIdx.x * 256;
    if (base + t < (long)NN * EMB) xs[t] = x[base + t];
    __syncthreads();
    int ln = t >> 6, c = t & 63;
    int node = blockIdx.x * 4 + ln;
    if (node >= NN) return;
    float aq = bq[c], ak = bk[c], av = bv[c];
    const float* xr = xs + ln * EMB;
#pragma unroll
    for (int i = 0; i < EMB; i++) {
        float xv = xr[i];
        aq += xv * Wq[i * EMB + c];
        ak += xv * Wk[i * EMB + c];
        av += xv * Wv[i * EMB + c];
    }
    q[(long)node * EMB + c] = aq;
    k[(long)node * EMB + c] = ak;
    v[(long)node * EMB + c] = av;
}

// ---- Edge pass: one thread per (edge, head). score -> exp -> atomic accumulate.
__global__ __launch_bounds__(256) void edge_kernel(
    const int* __restrict__ ei, const float* __restrict__ pos,
    const float* __restrict__ q, const float* __restrict__ k, const float* __restrict__ v,
    const float* __restrict__ relk, const float* __restrict__ relv,
    float* __restrict__ denom, float* __restrict__ accum, float* __restrict__ flags)
{
    long gid = (long)blockIdx.x * 256 + threadIdx.x;
    if (gid == 0) flags[1] = 1.0f;
    if (gid >= (long)NE * NH) return;
    int e = (int)(gid >> 3), h = (int)(gid & 7);
    int row = ei[e], col = ei[NE + e];
    if ((unsigned)row >= NN || (unsigned)col >= NN) { atomicAdd(&flags[3], 1.0f); return; }

    float dx = pos[row * 3 + 0] - pos[col * 3 + 0];
    float dy = pos[row * 3 + 1] - pos[col * 3 + 1];
    float dz = pos[row * 3 + 2] - pos[col * 3 + 2];
    float dist = sqrtf(dx * dx + dy * dy + dz * dz);
    int bin = (int)(dist * 10.0f);            // trunc toward zero; matches .astype(int32)
    bin = bin < 0 ? 0 : (bin > MAXD ? MAXD : bin);
    bin += MAXD;

    const float* qr = q + (long)row * EMB + h * HD;
    const float* kc = k + (long)col * EMB + h * HD;
    const float* rk = relk + ((long)bin * NH + h) * HD;
    float s = 0.0f;
#pragma unroll
    for (int i = 0; i < HD; i++) s += qr[i] * (kc[i] + rk[i]);
    float ex = __expf(s * SCALE);             // softmax shift-invariant: no max needed

    atomicAdd(&denom[(long)row * NH + h], ex);

    const float* vc = v + (long)col * EMB + h * HD;
    const float* rv = relv + ((long)bin * NH + h) * HD;
    float* ar = accum + (long)row * EMB + h * HD;
#pragma unroll
    for (int i = 0; i < HD; i++) atomicAdd(ar + i, ex * (vc[i] + rv[i]));
}

// ---- Output: normalize, @ Wo + bo; 4 nodes per 256-thread block. Sentinel ladder.
__global__ __launch_bounds__(256) void out_kernel(
    const float* __restrict__ accum, const float* __restrict__ denom,
    const float* __restrict__ q, const float* __restrict__ k, const float* __restrict__ v,
    const float* __restrict__ Wo, const float* __restrict__ bo,
    const float* __restrict__ flags, float* __restrict__ out)
{
    __shared__ float ys[4 * EMB];
    __shared__ int cls[4];
    int t = threadIdx.x, ln = t >> 6, c = t & 63;
    int node = blockIdx.x * 4 + ln;
    if (c == 0) cls[ln] = 0;
    __syncthreads();
    if (node < NN) {
        float den = denom[(long)node * NH + (c >> 3)];
        float a = accum[(long)node * EMB + c];
        int cl = 0;
        if (den != den) cl = 7;                 // NaN
        else if (den == 0.0f) cl = 6;           // no edge landed
        else if (isinf(den)) cl = 5;
        else if (den < 0.0f) cl = 4;
        float qv = q[(long)node * EMB + c], kv = k[(long)node * EMB + c],
              vv = v[(long)node * EMB + c];
        if (cl == 0 && (!isfinite(qv) || !isfinite(kv) || !isfinite(vv))) cl = 3;
        ys[t] = (den > 0.0f) ? a / den : 0.0f;
        if (cl) atomicMax(&cls[ln], cl);
    }
    __syncthreads();
    if (node >= NN) return;
    float sent = 0.0f;
    if (flags[6] > 900.0f) sent = 990.0f;       // edge_index looks int64
    else if (flags[5] < 512.0f) sent = 940.0f;  // x does NOT look fp32 (bf16 after all?)
    else if (flags[1] == 0.0f) sent = 900.0f;   // edge kernel never ran
    else if (flags[0] == 0.0f) sent = 850.0f;   // qkv never ran
    else if (flags[3] > 0.0f) sent = 800.0f;    // row/col out of range
    else if (cls[ln] > 0) sent = 100.0f * cls[ln];
    if (sent > 0.0f) { out[(long)node * EMB + c] = sent; return; }
    float acc = bo[c];
    const float* yr = ys + ln * EMB;
#pragma unroll
    for (int i = 0; i < EMB; i++) acc += yr[i] * Wo[i * EMB + c];
    out[(long)node * EMB + c] = acc;
}

extern "C" void kernel_launch(void* const* d_in, const int* in_sizes, int n_in,
                              void* d_out, int out_size, void* d_ws, size_t ws_size,
                              hipStream_t stream) {
    float* out = (float*)d_out;
    long on = out_size;
    int ogrid = (int)((on + 255) / 256);

    if (n_in != 13) { fill_kernel<<<ogrid, 256, 0, stream>>>(out, on, 3000.0f); return; }
    const int want[13] = {NN * EMB, 2 * NE, NN * 3, EMB * EMB, EMB, EMB * EMB, EMB,
                          EMB * EMB, EMB, (2 * MAXD + 1) * EMB, (2 * MAXD + 1) * EMB,
                          EMB * EMB, EMB};
    for (int i = 0; i < 13; i++)
        if (in_sizes[i] != want[i]) { fill_kernel<<<ogrid, 256, 0, stream>>>(out, on, 2000.0f); return; }
    size_t need = ((size_t)NN * EMB * 4 + (size_t)NN * NH + 16) * sizeof(float);
    if (ws_size < need) { fill_kernel<<<ogrid, 256, 0, stream>>>(out, on, 1000.0f); return; }

    const float* x    = (const float*)d_in[0];
    const int*   ei   = (const int*)d_in[1];
    const float* pos  = (const float*)d_in[2];
    const float* Wq   = (const float*)d_in[3];
    const float* bq   = (const float*)d_in[4];
    const float* Wk   = (const float*)d_in[5];
    const float* bk   = (const float*)d_in[6];
    const float* Wv   = (const float*)d_in[7];
    const float* bv   = (const float*)d_in[8];
    const float* relk = (const float*)d_in[9];
    const float* relv = (const float*)d_in[10];
    const float* Wo   = (const float*)d_in[11];
    const float* bo   = (const float*)d_in[12];

    float* ws    = (float*)d_ws;
    float* accum = ws;                        // NN*EMB
    float* denom = accum + (long)NN * EMB;    // NN*NH (contiguous with accum)
    float* q     = denom + (long)NN * NH;     // NN*EMB
    float* k     = q + (long)NN * EMB;        // NN*EMB
    float* v     = k + (long)NN * EMB;        // NN*EMB
    float* flags = v + (long)NN * EMB;        // 16

    long zn = (long)NN * (EMB + NH);
    init_kernel<<<(int)((zn + 255) / 256), 256, 0, stream>>>(accum, zn);
    sniff_kernel<<<1, 256, 0, stream>>>((const unsigned*)x, ei, flags);
    qkv_kernel<<<(NN + 3) / 4, 256, 0, stream>>>(x, Wq, bq, Wk, bk, Wv, bv, q, k, v, flags);
    edge_kernel<<<(int)(((long)NE * NH + 255) / 256), 256, 0, stream>>>(
        ei, pos, q, k, v, relk, relv, denom, accum, flags);
    out_kernel<<<(NN + 3) / 4, 256, 0, stream>>>(accum, denom, q, k, v, Wo, bo, flags, out);
}

// Round 5
// 437.838 us; speedup vs baseline: 3.8822x; 3.8822x over previous
//
#include <hip/hip_runtime.h>

#define NN 50000
#define NE 800000
#define EMB 64
#define NH 8
#define HD 8
#define MAXD 100
#define SCALE 0.35355339059327373f

// ws layout:
//   q[NN*EMB] f32 | k[NN*EMB] f32 | v[NN*EMB] f32 |
//   cnt[NN] i32 | rowstart[NN+1] i32 | wofs[NN] i32 | epack[NE] i32

__global__ __launch_bounds__(256) void fill_kernel(float* __restrict__ out, long n, float val) {
    long i = (long)blockIdx.x * 256 + threadIdx.x;
    if (i < n) out[i] = val;
}

__global__ __launch_bounds__(256) void zero_kernel(int* __restrict__ p, int n) {
    int i = blockIdx.x * 256 + threadIdx.x;
    if (i < n) p[i] = 0;
}

// ---- QKV: per-node y = x @ W + b; 4 nodes per 256-thread block
__global__ __launch_bounds__(256) void qkv_kernel(
    const float* __restrict__ x,
    const float* __restrict__ Wq, const float* __restrict__ bq,
    const float* __restrict__ Wk, const float* __restrict__ bk,
    const float* __restrict__ Wv, const float* __restrict__ bv,
    float* __restrict__ q, float* __restrict__ k, float* __restrict__ v)
{
    __shared__ float xs[4 * EMB];
    int t = threadIdx.x;
    long base = (long)blockIdx.x * 256;
    if (base + t < (long)NN * EMB) xs[t] = x[base + t];
    __syncthreads();
    int ln = t >> 6, c = t & 63;
    int node = blockIdx.x * 4 + ln;
    if (node >= NN) return;
    float aq = bq[c], ak = bk[c], av = bv[c];
    const float* xr = xs + ln * EMB;
#pragma unroll
    for (int i = 0; i < EMB; i++) {
        float xv = xr[i];
        aq += xv * Wq[i * EMB + c];
        ak += xv * Wk[i * EMB + c];
        av += xv * Wv[i * EMB + c];
    }
    q[(long)node * EMB + c] = aq;
    k[(long)node * EMB + c] = ak;
    v[(long)node * EMB + c] = av;
}

// ---- in-degree histogram (int atomics: cheap)
__global__ __launch_bounds__(256) void hist_kernel(const int* __restrict__ ei,
                                                   int* __restrict__ cnt) {
    int e = blockIdx.x * 256 + threadIdx.x;
    if (e < NE) atomicAdd(&cnt[ei[e]], 1);
}

// ---- exclusive prefix sum over cnt[NN] -> rowstart[NN+1], copy to wofs. Single block.
__global__ __launch_bounds__(1024) void scan_kernel(const int* __restrict__ cnt,
                                                    int* __restrict__ rowstart,
                                                    int* __restrict__ wofs) {
    __shared__ int wsum[16];
    __shared__ int carry_s;
    int t = threadIdx.x, lane = t & 63, wid = t >> 6;
    if (t == 0) carry_s = 0;
    __syncthreads();
    for (int base = 0; base < NN; base += 1024) {
        int idx = base + t;
        int val = (idx < NN) ? cnt[idx] : 0;
        int s = val;
#pragma unroll
        for (int off = 1; off < 64; off <<= 1) {
            int n = __shfl_up(s, off, 64);
            if (lane >= off) s += n;
        }
        if (lane == 63) wsum[wid] = s;
        __syncthreads();
        if (wid == 0) {
            int ws = (lane < 16) ? wsum[lane] : 0;
#pragma unroll
            for (int off = 1; off < 16; off <<= 1) {
                int n = __shfl_up(ws, off, 64);
                if (lane >= off) ws += n;
            }
            if (lane < 16) wsum[lane] = ws;   // inclusive scan of wave totals
        }
        __syncthreads();
        int waveExcl = (wid > 0) ? wsum[wid - 1] : 0;
        int excl = carry_s + waveExcl + s - val;
        if (idx < NN) { rowstart[idx] = excl; wofs[idx] = excl; }
        int chunkTot = wsum[15];
        __syncthreads();
        if (t == 0) carry_s += chunkTot;
        __syncthreads();
    }
    if (t == 0) rowstart[NN] = carry_s;
}

// ---- scatter edges into CSR slots, packing col (16b) | bin (upper bits)
__global__ __launch_bounds__(256) void scatter_kernel(const int* __restrict__ ei,
                                                      const float* __restrict__ pos,
                                                      int* __restrict__ wofs,
                                                      int* __restrict__ epack) {
    int e = blockIdx.x * 256 + threadIdx.x;
    if (e >= NE) return;
    int row = ei[e], col = ei[NE + e];
    float dx = pos[row * 3 + 0] - pos[col * 3 + 0];
    float dy = pos[row * 3 + 1] - pos[col * 3 + 1];
    float dz = pos[row * 3 + 2] - pos[col * 3 + 2];
    float dist = sqrtf(dx * dx + dy * dy + dz * dz);
    int bin = (int)(dist * 10.0f);           // dist >= 0 -> bin >= 0; trunc = .astype(int32)
    bin = bin > MAXD ? MAXD : bin;
    bin += MAXD;
    int slot = atomicAdd(&wofs[row], 1);
    epack[slot] = col | (bin << 16);
}

// ---- fused gather + softmax + PV + output GEMV. One wave per node; lane = channel.
__global__ __launch_bounds__(256) void node_kernel(
    const int* __restrict__ rowstart, const int* __restrict__ epack,
    const float* __restrict__ q, const float* __restrict__ k, const float* __restrict__ v,
    const float* __restrict__ relk, const float* __restrict__ relv,
    const float* __restrict__ Wo, const float* __restrict__ bo,
    float* __restrict__ out)
{
    __shared__ float ys[4][EMB];
    int t = threadIdx.x, ln = t >> 6, i = t & 63;
    int node = blockIdx.x * 4 + ln;
    if (node < NN) {
        float qi = q[(long)node * EMB + i];
        float num = 0.0f, den = 0.0f;
        int s0 = rowstart[node], s1 = rowstart[node + 1];
        for (int j = s0; j < s1; j++) {
            int pk = epack[j];               // same addr across wave -> broadcast
            int col = pk & 0xFFFF;
            int bin = pk >> 16;
            float p = qi * (k[(long)col * EMB + i] + relk[bin * EMB + i]);
            p += __shfl_xor(p, 1, 64);       // reduce within 8-lane head group
            p += __shfl_xor(p, 2, 64);
            p += __shfl_xor(p, 4, 64);
            float ex = __expf(p * SCALE);    // softmax shift-invariant; scores bounded
            den += ex;
            num += ex * (v[(long)col * EMB + i] + relv[bin * EMB + i]);
        }
        ys[ln][i] = (den > 0.0f) ? num / den : 0.0f;
    } else {
        ys[ln][i] = 0.0f;
    }
    __syncthreads();
    if (node >= NN) return;
    float acc = bo[i];
    const float* yr = ys[ln];
#pragma unroll
    for (int jj = 0; jj < EMB; jj++) acc += yr[jj] * Wo[jj * EMB + i];
    out[(long)node * EMB + i] = acc;
}

extern "C" void kernel_launch(void* const* d_in, const int* in_sizes, int n_in,
                              void* d_out, int out_size, void* d_ws, size_t ws_size,
                              hipStream_t stream) {
    float* out = (float*)d_out;
    long on = out_size;
    int ogrid = (int)((on + 255) / 256);

    if (n_in != 13) { fill_kernel<<<ogrid, 256, 0, stream>>>(out, on, 3000.0f); return; }
    size_t need = ((size_t)NN * EMB * 3 + 3 * NN + 1 + NE) * sizeof(float) + 256;
    if (ws_size < need) { fill_kernel<<<ogrid, 256, 0, stream>>>(out, on, 1000.0f); return; }

    const float* x    = (const float*)d_in[0];
    const int*   ei   = (const int*)d_in[1];
    const float* pos  = (const float*)d_in[2];
    const float* Wq   = (const float*)d_in[3];
    const float* bq   = (const float*)d_in[4];
    const float* Wk   = (const float*)d_in[5];
    const float* bk   = (const float*)d_in[6];
    const float* Wv   = (const float*)d_in[7];
    const float* bv   = (const float*)d_in[8];
    const float* relk = (const float*)d_in[9];
    const float* relv = (const float*)d_in[10];
    const float* Wo   = (const float*)d_in[11];
    const float* bo   = (const float*)d_in[12];

    float* ws       = (float*)d_ws;
    float* q        = ws;                        // NN*EMB
    float* k        = q + (long)NN * EMB;        // NN*EMB
    float* v        = k + (long)NN * EMB;        // NN*EMB
    int*   cnt      = (int*)(v + (long)NN * EMB);// NN
    int*   rowstart = cnt + NN;                  // NN+1
    int*   wofs     = rowstart + NN + 1;         // NN
    int*   epack    = wofs + NN;                 // NE

    zero_kernel<<<(NN + 255) / 256, 256, 0, stream>>>(cnt, NN);
    qkv_kernel<<<(NN + 3) / 4, 256, 0, stream>>>(x, Wq, bq, Wk, bk, Wv, bv, q, k, v);
    hist_kernel<<<(NE + 255) / 256, 256, 0, stream>>>(ei, cnt);
    scan_kernel<<<1, 1024, 0, stream>>>(cnt, rowstart, wofs);
    scatter_kernel<<<(NE + 255) / 256, 256, 0, stream>>>(ei, pos, wofs, epack);
    node_kernel<<<(NN + 3) / 4, 256, 0, stream>>>(rowstart, epack, q, k, v,
                                                  relk, relv, Wo, bo, out);
}

// Round 6
// 398.983 us; speedup vs baseline: 4.2603x; 1.0974x over previous
//
#include <hip/hip_runtime.h>

#define NN 50000
#define NE 800000
#define EMB 64
#define NH 8
#define HD 8
#define MAXD 100
#define NBINS (2 * MAXD + 1)
#define SCALE 0.35355339059327373f
#define NB ((NN + 255) / 256)   // 196 scan blocks

__global__ __launch_bounds__(256) void fill_kernel(float* __restrict__ out, long n, float val) {
    long i = (long)blockIdx.x * 256 + threadIdx.x;
    if (i < n) out[i] = val;
}

// ---- prep: zero cnt + interleave rel tables into float2
__global__ __launch_bounds__(256) void prep_kernel(const float* __restrict__ relk,
                                                   const float* __restrict__ relv,
                                                   float2* __restrict__ relc,
                                                   int* __restrict__ cnt) {
    int idx = blockIdx.x * 256 + threadIdx.x;
    if (idx < NN) cnt[idx] = 0;
    if (idx < NBINS * EMB) relc[idx] = make_float2(relk[idx], relv[idx]);
}

// ---- QKV: q separate, k/v interleaved float2; 4 nodes per 256-thread block
__global__ __launch_bounds__(256) void qkv_kernel(
    const float* __restrict__ x,
    const float* __restrict__ Wq, const float* __restrict__ bq,
    const float* __restrict__ Wk, const float* __restrict__ bk,
    const float* __restrict__ Wv, const float* __restrict__ bv,
    float* __restrict__ q, float2* __restrict__ kv)
{
    __shared__ float xs[4 * EMB];
    int t = threadIdx.x;
    long base = (long)blockIdx.x * 256;
    if (base + t < (long)NN * EMB) xs[t] = x[base + t];
    __syncthreads();
    int ln = t >> 6, c = t & 63;
    int node = blockIdx.x * 4 + ln;
    if (node >= NN) return;
    float aq = bq[c], ak = bk[c], av = bv[c];
    const float* xr = xs + ln * EMB;
#pragma unroll
    for (int i = 0; i < EMB; i++) {
        float xv = xr[i];
        aq += xv * Wq[i * EMB + c];
        ak += xv * Wk[i * EMB + c];
        av += xv * Wv[i * EMB + c];
    }
    q[(long)node * EMB + c] = aq;
    kv[(long)node * EMB + c] = make_float2(ak, av);
}

// ---- in-degree histogram
__global__ __launch_bounds__(256) void hist_kernel(const int* __restrict__ ei,
                                                   int* __restrict__ cnt) {
    int e = blockIdx.x * 256 + threadIdx.x;
    if (e < NE) atomicAdd(&cnt[ei[e]], 1);
}

// ---- scan phase A: per-block exclusive scan into rowstart, block totals into bsum
__global__ __launch_bounds__(256) void scanA_kernel(const int* __restrict__ cnt,
                                                    int* __restrict__ rowstart,
                                                    int* __restrict__ bsum) {
    __shared__ int wsum[4];
    int t = threadIdx.x, lane = t & 63, wid = t >> 6;
    int idx = blockIdx.x * 256 + t;
    int val = (idx < NN) ? cnt[idx] : 0;
    int s = val;
#pragma unroll
    for (int off = 1; off < 64; off <<= 1) {
        int n = __shfl_up(s, off, 64);
        if (lane >= off) s += n;
    }
    if (lane == 63) wsum[wid] = s;
    __syncthreads();
    int wex = 0;
#pragma unroll
    for (int w = 0; w < 4; w++) if (w < wid) wex += wsum[w];
    int excl = wex + s - val;
    if (idx < NN) rowstart[idx] = excl;
    if (t == 255) bsum[blockIdx.x] = wex + s;
}

// ---- scan phase B: one block scans the NB block totals -> bofs (exclusive)
__global__ __launch_bounds__(256) void scanB_kernel(const int* __restrict__ bsum,
                                                    int* __restrict__ bofs) {
    __shared__ int wsum[4];
    int t = threadIdx.x, lane = t & 63, wid = t >> 6;
    int val = (t < NB) ? bsum[t] : 0;
    int s = val;
#pragma unroll
    for (int off = 1; off < 64; off <<= 1) {
        int n = __shfl_up(s, off, 64);
        if (lane >= off) s += n;
    }
    if (lane == 63) wsum[wid] = s;
    __syncthreads();
    int wex = 0;
#pragma unroll
    for (int w = 0; w < 4; w++) if (w < wid) wex += wsum[w];
    if (t < NB) bofs[t] = wex + s - val;
}

// ---- scan phase C: add block offsets; duplicate into wofs cursor array
__global__ __launch_bounds__(256) void scanC_kernel(int* __restrict__ rowstart,
                                                    const int* __restrict__ bofs,
                                                    int* __restrict__ wofs) {
    int idx = blockIdx.x * 256 + threadIdx.x;
    if (idx < NN) {
        int r = rowstart[idx] + bofs[blockIdx.x];
        rowstart[idx] = r;
        wofs[idx] = r;
    }
    if (idx == 0) rowstart[NN] = NE;
}

// ---- scatter edges into CSR slots, packing col (low 16) | bin (high bits)
__global__ __launch_bounds__(256) void scatter_kernel(const int* __restrict__ ei,
                                                      const float* __restrict__ pos,
                                                      int* __restrict__ wofs,
                                                      int* __restrict__ epack) {
    int e = blockIdx.x * 256 + threadIdx.x;
    if (e >= NE) return;
    int row = ei[e], col = ei[NE + e];
    float dx = pos[row * 3 + 0] - pos[col * 3 + 0];
    float dy = pos[row * 3 + 1] - pos[col * 3 + 1];
    float dz = pos[row * 3 + 2] - pos[col * 3 + 2];
    float dist = sqrtf(dx * dx + dy * dy + dz * dz);
    int bin = (int)(dist * 10.0f);           // dist >= 0; trunc matches .astype(int32)
    bin = bin > MAXD ? MAXD : bin;
    bin += MAXD;
    int slot = atomicAdd(&wofs[row], 1);
    epack[slot] = col | (bin << 16);
}

// ---- fused gather + softmax + PV + output GEMV. One wave per node; lane = channel.
// Depth-1 software pipeline: next edge's gathers issued before this edge's exp chain.
__global__ __launch_bounds__(256) void node_kernel(
    const int* __restrict__ rowstart, const int* __restrict__ epack,
    const float* __restrict__ q, const float2* __restrict__ kv,
    const float2* __restrict__ relc,
    const float* __restrict__ Wo, const float* __restrict__ bo,
    float* __restrict__ out)
{
    __shared__ float ys[4][EMB];
    int t = threadIdx.x, ln = t >> 6, i = t & 63;
    int node = blockIdx.x * 4 + ln;
    if (node < NN) {
        float qi = q[(long)node * EMB + i];
        float num = 0.0f, den = 0.0f;
        int s0 = rowstart[node], s1 = rowstart[node + 1];
        if (s0 < s1) {
            int pk = epack[s0];
            float2 kvc = kv[(long)(pk & 0xFFFF) * EMB + i];
            float2 rr  = relc[(pk >> 16) * EMB + i];
            for (int j = s0 + 1; j < s1; j++) {
                int pk2 = epack[j];                       // prefetch next edge
                float2 kv2 = kv[(long)(pk2 & 0xFFFF) * EMB + i];
                float2 r2  = relc[(pk2 >> 16) * EMB + i];
                float p = qi * (kvc.x + rr.x);
                p += __shfl_xor(p, 1, 64);
                p += __shfl_xor(p, 2, 64);
                p += __shfl_xor(p, 4, 64);
                float ex = __expf(p * SCALE);
                den += ex;
                num += ex * (kvc.y + rr.y);
                kvc = kv2; rr = r2;
            }
            float p = qi * (kvc.x + rr.x);
            p += __shfl_xor(p, 1, 64);
            p += __shfl_xor(p, 2, 64);
            p += __shfl_xor(p, 4, 64);
            float ex = __expf(p * SCALE);
            den += ex;
            num += ex * (kvc.y + rr.y);
        }
        ys[ln][i] = (den > 0.0f) ? num / den : 0.0f;
    } else {
        ys[ln][i] = 0.0f;
    }
    __syncthreads();
    if (node >= NN) return;
    float acc = bo[i];
    const float* yr = ys[ln];
#pragma unroll
    for (int jj = 0; jj < EMB; jj++) acc += yr[jj] * Wo[jj * EMB + i];
    out[(long)node * EMB + i] = acc;
}

extern "C" void kernel_launch(void* const* d_in, const int* in_sizes, int n_in,
                              void* d_out, int out_size, void* d_ws, size_t ws_size,
                              hipStream_t stream) {
    float* out = (float*)d_out;
    long on = out_size;
    int ogrid = (int)((on + 255) / 256);

    if (n_in != 13) { fill_kernel<<<ogrid, 256, 0, stream>>>(out, on, 3000.0f); return; }

    const float* x    = (const float*)d_in[0];
    const int*   ei   = (const int*)d_in[1];
    const float* pos  = (const float*)d_in[2];
    const float* Wq   = (const float*)d_in[3];
    const float* bq   = (const float*)d_in[4];
    const float* Wk   = (const float*)d_in[5];
    const float* bk   = (const float*)d_in[6];
    const float* Wv   = (const float*)d_in[7];
    const float* bv   = (const float*)d_in[8];
    const float* relk = (const float*)d_in[9];
    const float* relv = (const float*)d_in[10];
    const float* Wo   = (const float*)d_in[11];
    const float* bo   = (const float*)d_in[12];

    // ws layout (floats)
    float*  ws       = (float*)d_ws;
    float*  q        = ws;                          // NN*EMB           (3.2M)
    float2* kv       = (float2*)(q + (long)NN * EMB);      // NN*EMB float2 (6.4M floats)
    float2* relc     = kv + (long)NN * EMB;         // NBINS*EMB float2 (25728 floats)
    int*    cnt      = (int*)(relc + NBINS * EMB);  // NN
    int*    rowstart = cnt + NN;                    // NN+1
    int*    wofs     = rowstart + NN + 1;           // NN
    int*    bsum     = wofs + NN;                   // NB
    int*    bofs     = bsum + NB;                   // NB
    int*    epack    = bofs + NB;                   // NE

    size_t need = (size_t)((char*)(epack + NE) - (char*)d_ws);
    if (ws_size < need) { fill_kernel<<<ogrid, 256, 0, stream>>>(out, on, 1000.0f); return; }

    prep_kernel<<<NB, 256, 0, stream>>>(relk, relv, relc, cnt);
    qkv_kernel<<<(NN + 3) / 4, 256, 0, stream>>>(x, Wq, bq, Wk, bk, Wv, bv, q, kv);
    hist_kernel<<<(NE + 255) / 256, 256, 0, stream>>>(ei, cnt);
    scanA_kernel<<<NB, 256, 0, stream>>>(cnt, rowstart, bsum);
    scanB_kernel<<<1, 256, 0, stream>>>(bsum, bofs);
    scanC_kernel<<<NB, 256, 0, stream>>>(rowstart, bofs, wofs);
    scatter_kernel<<<(NE + 255) / 256, 256, 0, stream>>>(ei, pos, wofs, epack);
    node_kernel<<<(NN + 3) / 4, 256, 0, stream>>>(rowstart, epack, q, kv, relc, Wo, bo, out);
}

// Round 7
// 322.102 us; speedup vs baseline: 5.2771x; 1.2387x over previous
//
#include <hip/hip_runtime.h>
#include <hip/hip_fp16.h>

#define NN 50000
#define NE 800000
#define EMB 64
#define NH 8
#define HD 8
#define MAXD 100
#define NBINS (2 * MAXD + 1)
#define SCALE 0.35355339059327373f
#define NB ((NN + 255) / 256)   // 196 scan blocks

__global__ __launch_bounds__(256) void fill_kernel(float* __restrict__ out, long n, float val) {
    long i = (long)blockIdx.x * 256 + threadIdx.x;
    if (i < n) out[i] = val;
}

// ---- prep: zero cnt + pack rel tables into half2 (rk, rv)
__global__ __launch_bounds__(256) void prep_kernel(const float* __restrict__ relk,
                                                   const float* __restrict__ relv,
                                                   __half2* __restrict__ relh,
                                                   int* __restrict__ cnt) {
    int idx = blockIdx.x * 256 + threadIdx.x;
    if (idx < NN) cnt[idx] = 0;
    if (idx < NBINS * EMB) relh[idx] = __floats2half2_rn(relk[idx], relv[idx]);
}

// ---- QKV: 16 nodes/block, each wave computes 4 nodes sharing W loads.
// q fp32; k/v packed half2.
__global__ __launch_bounds__(256) void qkv_kernel(
    const float* __restrict__ x,
    const float* __restrict__ Wq, const float* __restrict__ bq,
    const float* __restrict__ Wk, const float* __restrict__ bk,
    const float* __restrict__ Wv, const float* __restrict__ bv,
    float* __restrict__ q, __half2* __restrict__ kvh)
{
    __shared__ float xs[16][EMB];
    int t = threadIdx.x;
    long base = (long)blockIdx.x * 16 * EMB;   // 3125*1024 == NN*EMB exactly
#pragma unroll
    for (int r = 0; r < 4; r++)
        ((float*)xs)[r * 256 + t] = x[base + r * 256 + t];
    __syncthreads();
    int ln = t >> 6, c = t & 63;
    int n0 = ln * 4;
    float bqc = bq[c], bkc = bk[c], bvc = bv[c];
    float aq[4], ak[4], av[4];
#pragma unroll
    for (int n = 0; n < 4; n++) { aq[n] = bqc; ak[n] = bkc; av[n] = bvc; }
#pragma unroll 8
    for (int i = 0; i < EMB; i++) {
        float wq = Wq[i * EMB + c], wk = Wk[i * EMB + c], wv = Wv[i * EMB + c];
#pragma unroll
        for (int n = 0; n < 4; n++) {
            float xv = xs[n0 + n][i];
            aq[n] += xv * wq; ak[n] += xv * wk; av[n] += xv * wv;
        }
    }
    long nodeBase = (long)blockIdx.x * 16 + n0;
#pragma unroll
    for (int n = 0; n < 4; n++) {
        q[(nodeBase + n) * EMB + c] = aq[n];
        kvh[(nodeBase + n) * EMB + c] = __floats2half2_rn(ak[n], av[n]);
    }
}

// ---- in-degree histogram
__global__ __launch_bounds__(256) void hist_kernel(const int* __restrict__ ei,
                                                   int* __restrict__ cnt) {
    int e = blockIdx.x * 256 + threadIdx.x;
    if (e < NE) atomicAdd(&cnt[ei[e]], 1);
}

// ---- scan A: per-block exclusive scan + block totals
__global__ __launch_bounds__(256) void scanA_kernel(const int* __restrict__ cnt,
                                                    int* __restrict__ rowstart,
                                                    int* __restrict__ bsum) {
    __shared__ int wsum[4];
    int t = threadIdx.x, lane = t & 63, wid = t >> 6;
    int idx = blockIdx.x * 256 + t;
    int val = (idx < NN) ? cnt[idx] : 0;
    int s = val;
#pragma unroll
    for (int off = 1; off < 64; off <<= 1) {
        int n = __shfl_up(s, off, 64);
        if (lane >= off) s += n;
    }
    if (lane == 63) wsum[wid] = s;
    __syncthreads();
    int wex = 0;
#pragma unroll
    for (int w = 0; w < 4; w++) if (w < wid) wex += wsum[w];
    if (idx < NN) rowstart[idx] = wex + s - val;
    if (t == 255) bsum[blockIdx.x] = wex + s;
}

// ---- scan B: one block scans NB block totals
__global__ __launch_bounds__(256) void scanB_kernel(const int* __restrict__ bsum,
                                                    int* __restrict__ bofs) {
    __shared__ int wsum[4];
    int t = threadIdx.x, lane = t & 63, wid = t >> 6;
    int val = (t < NB) ? bsum[t] : 0;
    int s = val;
#pragma unroll
    for (int off = 1; off < 64; off <<= 1) {
        int n = __shfl_up(s, off, 64);
        if (lane >= off) s += n;
    }
    if (lane == 63) wsum[wid] = s;
    __syncthreads();
    int wex = 0;
#pragma unroll
    for (int w = 0; w < 4; w++) if (w < wid) wex += wsum[w];
    if (t < NB) bofs[t] = wex + s - val;
}

// ---- scan C: add block offsets, duplicate cursor
__global__ __launch_bounds__(256) void scanC_kernel(int* __restrict__ rowstart,
                                                    const int* __restrict__ bofs,
                                                    int* __restrict__ wofs) {
    int idx = blockIdx.x * 256 + threadIdx.x;
    if (idx < NN) {
        int r = rowstart[idx] + bofs[blockIdx.x];
        rowstart[idx] = r;
        wofs[idx] = r;
    }
    if (idx == 0) rowstart[NN] = NE;
}

// ---- scatter edges into CSR slots: col (low 16) | bin (high bits)
__global__ __launch_bounds__(256) void scatter_kernel(const int* __restrict__ ei,
                                                      const float* __restrict__ pos,
                                                      int* __restrict__ wofs,
                                                      int* __restrict__ epack) {
    int e = blockIdx.x * 256 + threadIdx.x;
    if (e >= NE) return;
    int row = ei[e], col = ei[NE + e];
    float dx = pos[row * 3 + 0] - pos[col * 3 + 0];
    float dy = pos[row * 3 + 1] - pos[col * 3 + 1];
    float dz = pos[row * 3 + 2] - pos[col * 3 + 2];
    float dist = sqrtf(dx * dx + dy * dy + dz * dz);
    int bin = (int)(dist * 10.0f);
    bin = bin > MAXD ? MAXD : bin;
    bin += MAXD;
    int slot = atomicAdd(&wofs[row], 1);
    epack[slot] = col | (bin << 16);
}

// ---- fused gather + softmax + PV + output GEMV. One wave per node; lane = channel.
// Depth-2 prefetch; fp16 kv/rel gathers (4 B per lane per table per edge).
__global__ __launch_bounds__(256) void node_kernel(
    const int* __restrict__ rowstart, const int* __restrict__ epack,
    const float* __restrict__ q, const __half2* __restrict__ kvh,
    const __half2* __restrict__ relh,
    const float* __restrict__ Wo, const float* __restrict__ bo,
    float* __restrict__ out)
{
    __shared__ float ys[4][EMB];
    __shared__ float ps[4][4][EMB];
    int t = threadIdx.x, ln = t >> 6, i = t & 63;
    int node = blockIdx.x * 4 + ln;
    float num = 0.0f, den = 0.0f;
    if (node < NN) {
        float qi = q[(long)node * EMB + i];
        int s0 = rowstart[node], s1 = rowstart[node + 1];
        float2 kv0 = make_float2(0.f, 0.f), r0 = kv0, kv1 = kv0, r1 = kv0;
        if (s0 < s1) {
            int pk = epack[s0];
            kv0 = __half22float2(kvh[(long)(pk & 0xFFFF) * EMB + i]);
            r0  = __half22float2(relh[(pk >> 16) * EMB + i]);
        }
        if (s0 + 1 < s1) {
            int pk = epack[s0 + 1];
            kv1 = __half22float2(kvh[(long)(pk & 0xFFFF) * EMB + i]);
            r1  = __half22float2(relh[(pk >> 16) * EMB + i]);
        }
        for (int j = s0; j < s1; j++) {
            float2 kv2, r2;
            bool more = (j + 2 < s1);
            if (more) {
                int pk = epack[j + 2];
                kv2 = __half22float2(kvh[(long)(pk & 0xFFFF) * EMB + i]);
                r2  = __half22float2(relh[(pk >> 16) * EMB + i]);
            }
            float p = qi * (kv0.x + r0.x);
            p += __shfl_xor(p, 1, 64);
            p += __shfl_xor(p, 2, 64);
            p += __shfl_xor(p, 4, 64);
            float ex = __expf(p * SCALE);   // softmax shift-invariant; scores bounded
            den += ex;
            num += ex * (kv0.y + r0.y);
            kv0 = kv1; r0 = r1;
            if (more) { kv1 = kv2; r1 = r2; }
        }
    }
    ys[ln][i] = (den > 0.0f) ? num / den : 0.0f;
    __syncthreads();
    // epilogue: wave ln covers i-range [16*ln, 16*ln+16) for ALL 4 nodes (shares Wo loads)
    float acc0 = 0.f, acc1 = 0.f, acc2 = 0.f, acc3 = 0.f;
#pragma unroll 4
    for (int r = 0; r < 16; r++) {
        int ii = ln * 16 + r;
        float w = Wo[ii * EMB + i];
        acc0 += ys[0][ii] * w;
        acc1 += ys[1][ii] * w;
        acc2 += ys[2][ii] * w;
        acc3 += ys[3][ii] * w;
    }
    ps[ln][0][i] = acc0; ps[ln][1][i] = acc1; ps[ln][2][i] = acc2; ps[ln][3][i] = acc3;
    __syncthreads();
    if (node >= NN) return;
    out[(long)node * EMB + i] = bo[i] + ps[0][ln][i] + ps[1][ln][i] + ps[2][ln][i] + ps[3][ln][i];
}

extern "C" void kernel_launch(void* const* d_in, const int* in_sizes, int n_in,
                              void* d_out, int out_size, void* d_ws, size_t ws_size,
                              hipStream_t stream) {
    float* out = (float*)d_out;
    long on = out_size;
    int ogrid = (int)((on + 255) / 256);

    if (n_in != 13) { fill_kernel<<<ogrid, 256, 0, stream>>>(out, on, 3000.0f); return; }

    const float* x    = (const float*)d_in[0];
    const int*   ei   = (const int*)d_in[1];
    const float* pos  = (const float*)d_in[2];
    const float* Wq   = (const float*)d_in[3];
    const float* bq   = (const float*)d_in[4];
    const float* Wk   = (const float*)d_in[5];
    const float* bk   = (const float*)d_in[6];
    const float* Wv   = (const float*)d_in[7];
    const float* bv   = (const float*)d_in[8];
    const float* relk = (const float*)d_in[9];
    const float* relv = (const float*)d_in[10];
    const float* Wo   = (const float*)d_in[11];
    const float* bo   = (const float*)d_in[12];

    float*   ws       = (float*)d_ws;
    float*   q        = ws;                               // NN*EMB f32
    __half2* kvh      = (__half2*)(q + (long)NN * EMB);   // NN*EMB half2
    __half2* relh     = kvh + (long)NN * EMB;             // NBINS*EMB half2
    int*     cnt      = (int*)(relh + NBINS * EMB);       // NN
    int*     rowstart = cnt + NN;                         // NN+1
    int*     wofs     = rowstart + NN + 1;                // NN
    int*     bsum     = wofs + NN;                        // NB
    int*     bofs     = bsum + NB;                        // NB
    int*     epack    = bofs + NB;                        // NE

    size_t need = (size_t)((char*)(epack + NE) - (char*)d_ws);
    if (ws_size < need) { fill_kernel<<<ogrid, 256, 0, stream>>>(out, on, 1000.0f); return; }

    prep_kernel<<<NB, 256, 0, stream>>>(relk, relv, relh, cnt);
    qkv_kernel<<<NN / 16, 256, 0, stream>>>(x, Wq, bq, Wk, bk, Wv, bv, q, kvh);
    hist_kernel<<<(NE + 255) / 256, 256, 0, stream>>>(ei, cnt);
    scanA_kernel<<<NB, 256, 0, stream>>>(cnt, rowstart, bsum);
    scanB_kernel<<<1, 256, 0, stream>>>(bsum, bofs);
    scanC_kernel<<<NB, 256, 0, stream>>>(rowstart, bofs, wofs);
    scatter_kernel<<<(NE + 255) / 256, 256, 0, stream>>>(ei, pos, wofs, epack);
    node_kernel<<<(NN + 3) / 4, 256, 0, stream>>>(rowstart, epack, q, kvh, relh, Wo, bo, out);
}